// Round 4
// baseline (351.638 us; speedup 1.0000x reference)
//
#include <hip/hip_runtime.h>

#define B_SZ 2048
#define D_SZ 128
#define H_SZ 512
#define JC 8      // j-chunk length
#define NCH 16    // number of j-chunks
#define CPG 3     // fixup: chunks per thread-group
#define NGRP 5    // fixup: thread groups (1 + 15/CPG)

typedef _Float16 half8 __attribute__((ext_vector_type(8)));
typedef float floatx4 __attribute__((ext_vector_type(4)));
typedef unsigned int uint4v __attribute__((ext_vector_type(4)));

static __device__ __forceinline__ float tanh_fast(float x) {
  float e = __expf(2.0f * x);
  return 1.0f - 2.0f * __builtin_amdgcn_rcpf(e + 1.0f);
}

static __device__ __forceinline__ void split_pair(float a, float b,
                                                  unsigned int& hi,
                                                  unsigned int& lo) {
  auto h = __builtin_amdgcn_cvt_pkrtz(a, b);
  float ra = a - (float)h[0];
  float rb = b - (float)h[1];
  auto l = __builtin_amdgcn_cvt_pkrtz(ra, rb);
  hi = __builtin_bit_cast(unsigned int, h);
  lo = __builtin_bit_cast(unsigned int, l);
}

// ---- Merged prep: enc (blocks 0..255) + W2 split (blocks 256..4351) --------
__global__ __launch_bounds__(256) void prep_kernel(
    const float* __restrict__ W2s, _Float16* __restrict__ W2h,
    _Float16* __restrict__ W2l, const float* __restrict__ x,
    const float* __restrict__ We1, const float* __restrict__ be1,
    const float* __restrict__ We2, const float* __restrict__ be2,
    float* __restrict__ z) {
  const int t = threadIdx.x;
  if (blockIdx.x >= 256) {
    // ---- W2s fp32 -> tiled fp16 hi/lo: W2t[j][dt][kg][dl][k8] -------------
    const int idx = (blockIdx.x - 256) * 256 + t;   // (j,dt,kg,dl)
    const int dl = idx & 63, kg = (idx >> 6) & 63, dtj = idx >> 12;
    const int d = (dtj & 1) * 64 + dl, j = dtj >> 1;
    const float* src = W2s + ((size_t)j * D_SZ + d) * H_SZ + kg * 8;
    float4 a = *(const float4*)src;
    float4 b = *(const float4*)(src + 4);
    unsigned int h0, l0, h1, l1, h2, l2, h3, l3;
    split_pair(a.x, a.y, h0, l0); split_pair(a.z, a.w, h1, l1);
    split_pair(b.x, b.y, h2, l2); split_pair(b.z, b.w, h3, l3);
    ((uint4*)W2h)[idx] = make_uint4(h0, h1, h2, h3);   // idx*8 halves
    ((uint4*)W2l)[idx] = make_uint4(l0, l1, l2, l3);
    return;
  }
  // ---- Encoder (fp32 vector) ----------------------------------------------
  __shared__ float xs[8][132];
  __shared__ float hs[8][516];
  const int b0 = blockIdx.x * 8;
  {
    int r = t >> 5, c4 = t & 31;
    float4 v = ((const float4*)(x + (size_t)(b0 + r) * D_SZ))[c4];
    xs[r][c4 * 4 + 0] = v.x; xs[r][c4 * 4 + 1] = v.y;
    xs[r][c4 * 4 + 2] = v.z; xs[r][c4 * 4 + 3] = v.w;
  }
  __syncthreads();
  for (int hb = 0; hb < 2; ++hb) {
    const int h = t + hb * 256;
    float acc[8];
    float bias = be1[h];
#pragma unroll
    for (int r = 0; r < 8; ++r) acc[r] = bias;
    const float4* wp = (const float4*)(We1 + (size_t)h * D_SZ);
    for (int k4 = 0; k4 < 32; ++k4) {
      float4 wv = wp[k4];
#pragma unroll
      for (int r = 0; r < 8; ++r) {
        acc[r] = fmaf(wv.x, xs[r][k4 * 4 + 0], acc[r]);
        acc[r] = fmaf(wv.y, xs[r][k4 * 4 + 1], acc[r]);
        acc[r] = fmaf(wv.z, xs[r][k4 * 4 + 2], acc[r]);
        acc[r] = fmaf(wv.w, xs[r][k4 * 4 + 3], acc[r]);
      }
    }
#pragma unroll
    for (int r = 0; r < 8; ++r) {
      float u = acc[r];
      hs[r][h] = fmaxf(u, 0.2f * u);
    }
  }
  __syncthreads();
  {
    const int d = t & 127, rg = t >> 7;
    float acc[4];
    float bias = be2[d];
#pragma unroll
    for (int r = 0; r < 4; ++r) acc[r] = bias;
    const float4* wp = (const float4*)(We2 + (size_t)d * H_SZ);
    for (int k4 = 0; k4 < 128; ++k4) {
      float4 wv = wp[k4];
#pragma unroll
      for (int r = 0; r < 4; ++r) {
        int row = rg * 4 + r;
        acc[r] = fmaf(wv.x, hs[row][k4 * 4 + 0], acc[r]);
        acc[r] = fmaf(wv.y, hs[row][k4 * 4 + 1], acc[r]);
        acc[r] = fmaf(wv.z, hs[row][k4 * 4 + 2], acc[r]);
        acc[r] = fmaf(wv.w, hs[row][k4 * 4 + 3], acc[r]);
      }
    }
#pragma unroll
    for (int r = 0; r < 4; ++r) {
      z[(size_t)d * B_SZ + b0 + rg * 4 + r] = tanh_fast(acc[r]);
    }
  }
}

// ---- Phase 1: per-j-chunk local prefix sums --------------------------------
// Block 64b x 128d x 8j; 4 waves, wave tile 32b x 64d via A-exchange with
// pair partner (w^1) through parity double-buffered LDS.
// SOFTWARE PIPELINE (1 deep): at step s, MFMA[s] uses A[s] (own kept in
// registers from last step's build; partner ds_read BEFORE the barrier) and
// B[s] (global loads issued LAST step -> full-step latency cover). Between
// the partner-read and the barrier: issue B[s+1] + build/write A[s+1].
// Post-barrier phase is pure MFMA.
// Passes hl+lh share one accumulator (MFMA C-chaining): acc 96->64 VGPR,
// epilogue 3->2 adds.
__global__ __launch_bounds__(256, 2) void dec_kernel(
    const float* __restrict__ W1s, const float* __restrict__ b1s,
    const _Float16* __restrict__ W2h, const _Float16* __restrict__ W2l,
    const float* __restrict__ b2s, const float* __restrict__ z,
    float* __restrict__ out, float* __restrict__ T) {
  __shared__ float w1L[JC][512];
  __shared__ float b1L[JC][512];
  __shared__ float zL[JC][64];
  __shared__ float b2L[JC][128];
  __shared__ uint4v aHs[2][4][64];   // [step parity][builder wave][lane]
  __shared__ uint4v aLs[2][4][64];

  const int t = threadIdx.x, bx = blockIdx.x;
  const int jc = bx & 15, bt = bx >> 4;   // same jc -> same XCD (bx%8)
  const int b0 = bt * 64, j0 = jc * JC;

#pragma unroll
  for (int i = 0; i < 4; ++i) {
    int g = t + 256 * i;                    // float4 granule 0..1023
    int jr = g >> 7, col = (g & 127) * 4;
    *(float4*)&w1L[jr][col] = *(const float4*)(W1s + (size_t)(j0 + jr) * H_SZ + col);
    *(float4*)&b1L[jr][col] = *(const float4*)(b1s + (size_t)(j0 + jr) * H_SZ + col);
  }
  if (t < 128) {
    int jr = t >> 4, col = (t & 15) * 4;
    *(float4*)&zL[jr][col] = *(const float4*)(z + (size_t)(j0 + jr) * B_SZ + b0 + col);
  }
  {
    int jr = t >> 5, col = (t & 31) * 4;
    *(float4*)&b2L[jr][col] = *(const float4*)(b2s + (size_t)(j0 + jr) * D_SZ + col);
  }
  __syncthreads();

  const int lane = t & 63;
  const int quad = lane >> 4, l16 = lane & 15;
  const int w = t >> 6;                     // wave id
  const int h = w & 1;                      // d-half this wave outputs
  const int pw = w ^ 1;                     // pair partner (same 32-row pair)
  const int rowL = w * 16 + l16;            // own build row (local)
  const unsigned voff = (unsigned)(quad * 512 + l16 * 8);

  floatx4 acc[2][4][2];                     // [bf own/partner][df][hh, hl+lh]
#pragma unroll
  for (int a = 0; a < 2; ++a)
#pragma unroll
    for (int b = 0; b < 4; ++b)
#pragma unroll
      for (int p = 0; p < 2; ++p) acc[a][b][p] = (floatx4){0.f, 0.f, 0.f, 0.f};
  float bc[4] = {0.f, 0.f, 0.f, 0.f};

  half8 curh, curl, cb[8];
  // ---- pipeline prologue: build+publish A[0], load B[0] --------------------
  {
    const float zv = zL[0][rowL];
    const int ko = quad * 8;
    float4 wa = *(const float4*)&w1L[0][ko];
    float4 wc = *(const float4*)&w1L[0][ko + 4];
    float4 ba = *(const float4*)&b1L[0][ko];
    float4 bb = *(const float4*)&b1L[0][ko + 4];
    float h0 = fmaf(zv, wa.x, ba.x), h1 = fmaf(zv, wa.y, ba.y);
    float h2 = fmaf(zv, wa.z, ba.z), h3 = fmaf(zv, wa.w, ba.w);
    float h4 = fmaf(zv, wc.x, bb.x), h5 = fmaf(zv, wc.y, bb.y);
    float h6 = fmaf(zv, wc.z, bb.z), h7 = fmaf(zv, wc.w, bb.w);
    h0 = fmaxf(h0, 0.2f * h0); h1 = fmaxf(h1, 0.2f * h1);
    h2 = fmaxf(h2, 0.2f * h2); h3 = fmaxf(h3, 0.2f * h3);
    h4 = fmaxf(h4, 0.2f * h4); h5 = fmaxf(h5, 0.2f * h5);
    h6 = fmaxf(h6, 0.2f * h6); h7 = fmaxf(h7, 0.2f * h7);
    unsigned int a0, a1, a2, a3, x0, x1, x2, x3;
    split_pair(h0, h1, a0, x0); split_pair(h2, h3, a1, x1);
    split_pair(h4, h5, a2, x2); split_pair(h6, h7, a3, x3);
    aHs[0][w][lane] = (uint4v){a0, a1, a2, a3};
    aLs[0][w][lane] = (uint4v){x0, x1, x2, x3};
    curh = __builtin_bit_cast(half8, (uint4v){a0, a1, a2, a3});
    curl = __builtin_bit_cast(half8, (uint4v){x0, x1, x2, x3});
    const unsigned off = (unsigned)(j0 * 2 + h) * 32768u + voff;
    cb[0] = *(const half8*)(W2h + off);
    cb[1] = *(const half8*)(W2h + off + 128);
    cb[2] = *(const half8*)(W2h + off + 256);
    cb[3] = *(const half8*)(W2h + off + 384);
    cb[4] = *(const half8*)(W2l + off);
    cb[5] = *(const half8*)(W2l + off + 128);
    cb[6] = *(const half8*)(W2l + off + 256);
    cb[7] = *(const half8*)(W2l + off + 384);
  }
  __syncthreads();

#pragma unroll 2
  for (int s = 0; s < 128; ++s) {
    const int par = s & 1;
    const int jj = s >> 4;
    const int j = j0 + jj;

    // partner A[s] (published before the PREVIOUS barrier -> visible;
    // parity keeps it race-free vs this step's writes)
    uint4v pH = aHs[par][pw][lane];
    uint4v pL = aLs[par][pw][lane];

    half8 nb[8], nh, nl;
    if (s < 127) {
      const int sn = s + 1;
      const int jn = sn >> 4, kn = sn & 15;
      // prefetch B[s+1] (full step of latency cover)
      const unsigned off = (unsigned)((j0 + jn) * 2 + h) * 32768u +
                           (unsigned)(kn * 2048) + voff;
      nb[0] = *(const half8*)(W2h + off);
      nb[1] = *(const half8*)(W2h + off + 128);
      nb[2] = *(const half8*)(W2h + off + 256);
      nb[3] = *(const half8*)(W2h + off + 384);
      nb[4] = *(const half8*)(W2l + off);
      nb[5] = *(const half8*)(W2l + off + 128);
      nb[6] = *(const half8*)(W2l + off + 256);
      nb[7] = *(const half8*)(W2l + off + 384);
      // build A[s+1]
      const float zv = zL[jn][rowL];
      const int ko = kn * 32 + quad * 8;
      float4 wa = *(const float4*)&w1L[jn][ko];
      float4 wc = *(const float4*)&w1L[jn][ko + 4];
      float4 ba = *(const float4*)&b1L[jn][ko];
      float4 bb = *(const float4*)&b1L[jn][ko + 4];
      float h0 = fmaf(zv, wa.x, ba.x), h1 = fmaf(zv, wa.y, ba.y);
      float h2 = fmaf(zv, wa.z, ba.z), h3 = fmaf(zv, wa.w, ba.w);
      float h4 = fmaf(zv, wc.x, bb.x), h5 = fmaf(zv, wc.y, bb.y);
      float h6 = fmaf(zv, wc.z, bb.z), h7 = fmaf(zv, wc.w, bb.w);
      h0 = fmaxf(h0, 0.2f * h0); h1 = fmaxf(h1, 0.2f * h1);
      h2 = fmaxf(h2, 0.2f * h2); h3 = fmaxf(h3, 0.2f * h3);
      h4 = fmaxf(h4, 0.2f * h4); h5 = fmaxf(h5, 0.2f * h5);
      h6 = fmaxf(h6, 0.2f * h6); h7 = fmaxf(h7, 0.2f * h7);
      unsigned int a0, a1, a2, a3, x0, x1, x2, x3;
      split_pair(h0, h1, a0, x0); split_pair(h2, h3, a1, x1);
      split_pair(h4, h5, a2, x2); split_pair(h6, h7, a3, x3);
      aHs[sn & 1][w][lane] = (uint4v){a0, a1, a2, a3};
      aLs[sn & 1][w][lane] = (uint4v){x0, x1, x2, x3};
      nh = __builtin_bit_cast(half8, (uint4v){a0, a1, a2, a3});
      nl = __builtin_bit_cast(half8, (uint4v){x0, x1, x2, x3});
    }
    __syncthreads();
    half8 pah = __builtin_bit_cast(half8, pH);
    half8 pal = __builtin_bit_cast(half8, pL);

    // pure-MFMA phase: all operands ready (A in regs, B loaded last step)
#pragma unroll
    for (int df = 0; df < 4; ++df) {
      acc[0][df][0] = __builtin_amdgcn_mfma_f32_16x16x32_f16(curh, cb[df], acc[0][df][0], 0, 0, 0);
      acc[0][df][1] = __builtin_amdgcn_mfma_f32_16x16x32_f16(curh, cb[df + 4], acc[0][df][1], 0, 0, 0);
      acc[0][df][1] = __builtin_amdgcn_mfma_f32_16x16x32_f16(curl, cb[df], acc[0][df][1], 0, 0, 0);
      acc[1][df][0] = __builtin_amdgcn_mfma_f32_16x16x32_f16(pah, cb[df], acc[1][df][0], 0, 0, 0);
      acc[1][df][1] = __builtin_amdgcn_mfma_f32_16x16x32_f16(pah, cb[df + 4], acc[1][df][1], 0, 0, 0);
      acc[1][df][1] = __builtin_amdgcn_mfma_f32_16x16x32_f16(pal, cb[df], acc[1][df][1], 0, 0, 0);
    }

    if (s < 127) {   // rotate pipeline registers
      curh = nh; curl = nl;
#pragma unroll
      for (int i = 0; i < 8; ++i) cb[i] = nb[i];
    }

    if ((s & 15) == 15) {   // per-j epilogue (inclusive prefix within chunk)
#pragma unroll
      for (int df = 0; df < 4; ++df) bc[df] += b2L[jj][h * 64 + df * 16 + l16];
      const int dcol = h * 64 + l16;
      float* obase = out + (size_t)j * (B_SZ * D_SZ) + dcol;
#pragma unroll
      for (int bf = 0; bf < 2; ++bf) {
        const int rb = bf ? pw : w;
        const int brow = b0 + rb * 16 + quad * 4;
        float* orow = obase + (size_t)brow * D_SZ;
#pragma unroll
        for (int r = 0; r < 4; ++r) {
#pragma unroll
          for (int df = 0; df < 4; ++df) {
            float sv = (acc[bf][df][0][r] + acc[bf][df][1][r]) + bc[df];
            if (jc == 0) sv = tanh_fast(sv);
            orow[(size_t)r * D_SZ + df * 16] = sv;
          }
        }
      }
    }
  }

  if (jc < NCH - 1) {   // chunk totals for phase-2 carries
    const int dcol = h * 64 + l16;
    float* tbase = T + (size_t)jc * (B_SZ * D_SZ) + dcol;
#pragma unroll
    for (int bf = 0; bf < 2; ++bf) {
      const int rb = bf ? pw : w;
      const int brow = b0 + rb * 16 + quad * 4;
      float* trow = tbase + (size_t)brow * D_SZ;
#pragma unroll
      for (int r = 0; r < 4; ++r) {
#pragma unroll
        for (int df = 0; df < 4; ++df) {
          trow[(size_t)r * D_SZ + df * 16] =
              (acc[bf][df][0][r] + acc[bf][df][1][r]) + bc[df];
        }
      }
    }
  }
}

// ---- Phase 2: carry fixup + tanh for j >= JC -------------------------------
__global__ __launch_bounds__(256) void fixup_kernel(
    const float* __restrict__ T, float* __restrict__ out) {
  const int idx = blockIdx.x * 256 + threadIdx.x;
  const int d4 = idx & 31;
  const int b = (idx >> 5) & (B_SZ - 1);
  const int q = idx >> 16;                 // 0..NGRP-1
  const size_t stride = B_SZ * (D_SZ / 4);
  const size_t tix = (size_t)b * (D_SZ / 4) + d4;
  const float4* T4 = (const float4*)T;
  float4* O4 = (float4*)out;

  const int c0 = 1 + q * CPG;
  float4 carry = make_float4(0.f, 0.f, 0.f, 0.f);
  for (int c = 0; c < c0; ++c) {
    float4 tv = T4[(size_t)c * stride + tix];
    carry.x += tv.x; carry.y += tv.y; carry.z += tv.z; carry.w += tv.w;
  }
#pragma unroll
  for (int cc = 0; cc < CPG; ++cc) {
    const int c = c0 + cc;
    if (cc > 0) {
      float4 tv = T4[(size_t)(c - 1) * stride + tix];
      carry.x += tv.x; carry.y += tv.y; carry.z += tv.z; carry.w += tv.w;
    }
#pragma unroll
    for (int jj = 0; jj < JC; ++jj) {
      const int j = c * JC + jj;
      const size_t oix = ((size_t)j * B_SZ + b) * (D_SZ / 4) + d4;
      float4 s = O4[oix];
      s.x = tanh_fast(s.x + carry.x);
      s.y = tanh_fast(s.y + carry.y);
      s.z = tanh_fast(s.z + carry.z);
      s.w = tanh_fast(s.w + carry.w);
      O4[oix] = s;
    }
  }
}

extern "C" void kernel_launch(void* const* d_in, const int* in_sizes, int n_in,
                              void* d_out, int out_size, void* d_ws,
                              size_t ws_size, hipStream_t stream) {
  (void)in_sizes; (void)n_in; (void)out_size; (void)ws_size;
  const float* x   = (const float*)d_in[0];
  const float* We1 = (const float*)d_in[1];
  const float* be1 = (const float*)d_in[2];
  const float* We2 = (const float*)d_in[3];
  const float* be2 = (const float*)d_in[4];
  const float* W1s = (const float*)d_in[5];
  const float* b1s = (const float*)d_in[6];
  const float* W2s = (const float*)d_in[7];
  const float* b2s = (const float*)d_in[8];
  float* out = (float*)d_out;

  // ws: z 1MB | W2h 16MB | W2l 16MB | T 15MB  -> 48 MiB
  float* zws = (float*)d_ws;
  _Float16* W2h = (_Float16*)((char*)d_ws + (1u << 20));
  _Float16* W2l = (_Float16*)((char*)d_ws + (1u << 20) + (1u << 24));
  float* T = (float*)((char*)d_ws + (1u << 20) + (2u << 24));

  prep_kernel<<<4352, 256, 0, stream>>>(W2s, W2h, W2l, x, We1, be1, We2, be2, zws);
  dec_kernel<<<512, 256, 0, stream>>>(W1s, b1s, W2h, W2l, b2s, zws, out, T);
  fixup_kernel<<<NGRP * 256, 256, 0, stream>>>(T, out);
}

// Round 5
// 337.621 us; speedup vs baseline: 1.0415x; 1.0415x over previous
//
#include <hip/hip_runtime.h>

#define B_SZ 2048
#define D_SZ 128
#define H_SZ 512
#define JC 8      // j-chunk length
#define NCH 16    // number of j-chunks
#define CPG 3     // fixup: chunks per thread-group
#define NGRP 5    // fixup: thread groups (1 + 15/CPG)

typedef _Float16 half8 __attribute__((ext_vector_type(8)));
typedef float floatx4 __attribute__((ext_vector_type(4)));
typedef unsigned int uint4v __attribute__((ext_vector_type(4)));

static __device__ __forceinline__ float tanh_fast(float x) {
  float e = __expf(2.0f * x);
  return 1.0f - 2.0f * __builtin_amdgcn_rcpf(e + 1.0f);
}

static __device__ __forceinline__ void split_pair(float a, float b,
                                                  unsigned int& hi,
                                                  unsigned int& lo) {
  auto h = __builtin_amdgcn_cvt_pkrtz(a, b);
  float ra = a - (float)h[0];
  float rb = b - (float)h[1];
  auto l = __builtin_amdgcn_cvt_pkrtz(ra, rb);
  hi = __builtin_bit_cast(unsigned int, h);
  lo = __builtin_bit_cast(unsigned int, l);
}

// ---- Merged prep: enc (blocks 0..255) + W2 split (blocks 256..2303) --------
// Split remapped: thread = (dtj, kg2, dl) -> each lane reads 64B contiguous
// 64B-aligned (zero over-fetch, was 32B@2KB stride = 2x amp) and writes
// stay fully coalesced (lane = dl -> contiguous uint4 runs). Memory layout
// of W2h/W2l is IDENTICAL to before; dec untouched.
__global__ __launch_bounds__(256) void prep_kernel(
    const float* __restrict__ W2s, _Float16* __restrict__ W2h,
    _Float16* __restrict__ W2l, const float* __restrict__ x,
    const float* __restrict__ We1, const float* __restrict__ be1,
    const float* __restrict__ We2, const float* __restrict__ be2,
    float* __restrict__ z) {
  const int t = threadIdx.x;
  if (blockIdx.x >= 256) {
    const int u = (blockIdx.x - 256) * 256 + t;   // (dtj, kg2, dl)
    const int dl = u & 63, kg2 = (u >> 6) & 31, dtj = u >> 11;
    const int d = (dtj & 1) * 64 + dl, j = dtj >> 1;
    const float* src = W2s + ((size_t)j * D_SZ + d) * H_SZ + kg2 * 16;
    float4 a0 = ((const float4*)src)[0];
    float4 a1 = ((const float4*)src)[1];
    float4 a2 = ((const float4*)src)[2];
    float4 a3 = ((const float4*)src)[3];
    unsigned int h0, l0, h1, l1, h2, l2, h3, l3;
    // octet kg = kg2*2
    split_pair(a0.x, a0.y, h0, l0); split_pair(a0.z, a0.w, h1, l1);
    split_pair(a1.x, a1.y, h2, l2); split_pair(a1.z, a1.w, h3, l3);
    const int idx0 = dtj * 4096 + (kg2 * 2) * 64 + dl;
    ((uint4*)W2h)[idx0] = make_uint4(h0, h1, h2, h3);
    ((uint4*)W2l)[idx0] = make_uint4(l0, l1, l2, l3);
    // octet kg = kg2*2+1
    split_pair(a2.x, a2.y, h0, l0); split_pair(a2.z, a2.w, h1, l1);
    split_pair(a3.x, a3.y, h2, l2); split_pair(a3.z, a3.w, h3, l3);
    const int idx1 = idx0 + 64;
    ((uint4*)W2h)[idx1] = make_uint4(h0, h1, h2, h3);
    ((uint4*)W2l)[idx1] = make_uint4(l0, l1, l2, l3);
    return;
  }
  // ---- Encoder (fp32 vector) ----------------------------------------------
  __shared__ float xs[8][132];
  __shared__ float hs[8][516];
  const int b0 = blockIdx.x * 8;
  {
    int r = t >> 5, c4 = t & 31;
    float4 v = ((const float4*)(x + (size_t)(b0 + r) * D_SZ))[c4];
    xs[r][c4 * 4 + 0] = v.x; xs[r][c4 * 4 + 1] = v.y;
    xs[r][c4 * 4 + 2] = v.z; xs[r][c4 * 4 + 3] = v.w;
  }
  __syncthreads();
  for (int hb = 0; hb < 2; ++hb) {
    const int h = t + hb * 256;
    float acc[8];
    float bias = be1[h];
#pragma unroll
    for (int r = 0; r < 8; ++r) acc[r] = bias;
    const float4* wp = (const float4*)(We1 + (size_t)h * D_SZ);
    for (int k4 = 0; k4 < 32; ++k4) {
      float4 wv = wp[k4];
#pragma unroll
      for (int r = 0; r < 8; ++r) {
        acc[r] = fmaf(wv.x, xs[r][k4 * 4 + 0], acc[r]);
        acc[r] = fmaf(wv.y, xs[r][k4 * 4 + 1], acc[r]);
        acc[r] = fmaf(wv.z, xs[r][k4 * 4 + 2], acc[r]);
        acc[r] = fmaf(wv.w, xs[r][k4 * 4 + 3], acc[r]);
      }
    }
#pragma unroll
    for (int r = 0; r < 8; ++r) {
      float u = acc[r];
      hs[r][h] = fmaxf(u, 0.2f * u);
    }
  }
  __syncthreads();
  {
    const int d = t & 127, rg = t >> 7;
    float acc[4];
    float bias = be2[d];
#pragma unroll
    for (int r = 0; r < 4; ++r) acc[r] = bias;
    const float4* wp = (const float4*)(We2 + (size_t)d * H_SZ);
    for (int k4 = 0; k4 < 128; ++k4) {
      float4 wv = wp[k4];
#pragma unroll
      for (int r = 0; r < 4; ++r) {
        int row = rg * 4 + r;
        acc[r] = fmaf(wv.x, hs[row][k4 * 4 + 0], acc[r]);
        acc[r] = fmaf(wv.y, hs[row][k4 * 4 + 1], acc[r]);
        acc[r] = fmaf(wv.z, hs[row][k4 * 4 + 2], acc[r]);
        acc[r] = fmaf(wv.w, hs[row][k4 * 4 + 3], acc[r]);
      }
    }
#pragma unroll
    for (int r = 0; r < 4; ++r) {
      z[(size_t)d * B_SZ + b0 + rg * 4 + r] = tanh_fast(acc[r]);
    }
  }
}

// ---- Phase 1: per-j-chunk local prefix sums (R3 structure, best) -----------
// Block 64b x 128d x 8j; 4 waves. Wave w builds A for rows w*16..+16 (ONE
// A-build per ks), exchanges frags with pair partner (w^1) through
// parity double-buffered LDS, computes a 32b x 64d tile (d-half = w&1).
__global__ __launch_bounds__(256, 2) void dec_kernel(
    const float* __restrict__ W1s, const float* __restrict__ b1s,
    const _Float16* __restrict__ W2h, const _Float16* __restrict__ W2l,
    const float* __restrict__ b2s, const float* __restrict__ z,
    float* __restrict__ out, float* __restrict__ T) {
  __shared__ float w1L[JC][512];
  __shared__ float b1L[JC][512];
  __shared__ float zL[JC][64];
  __shared__ float b2L[JC][128];
  __shared__ uint4v aHs[2][4][64];   // [ks parity][builder wave][lane]
  __shared__ uint4v aLs[2][4][64];

  const int t = threadIdx.x, bx = blockIdx.x;
  const int jc = bx & 15, bt = bx >> 4;   // same jc -> same XCD (bx%8)
  const int b0 = bt * 64, j0 = jc * JC;

#pragma unroll
  for (int i = 0; i < 4; ++i) {
    int g = t + 256 * i;                    // float4 granule 0..1023
    int jr = g >> 7, col = (g & 127) * 4;
    *(float4*)&w1L[jr][col] = *(const float4*)(W1s + (size_t)(j0 + jr) * H_SZ + col);
    *(float4*)&b1L[jr][col] = *(const float4*)(b1s + (size_t)(j0 + jr) * H_SZ + col);
  }
  if (t < 128) {
    int jr = t >> 4, col = (t & 15) * 4;
    *(float4*)&zL[jr][col] = *(const float4*)(z + (size_t)(j0 + jr) * B_SZ + b0 + col);
  }
  {
    int jr = t >> 5, col = (t & 31) * 4;
    *(float4*)&b2L[jr][col] = *(const float4*)(b2s + (size_t)(j0 + jr) * D_SZ + col);
  }
  __syncthreads();

  const int lane = t & 63;
  const int quad = lane >> 4, l16 = lane & 15;
  const int w = t >> 6;                     // wave id
  const int h = w & 1;                      // d-half this wave outputs
  const int pw = w ^ 1;                     // pair partner (same 32-row pair)

  floatx4 acc[2][4][3];                     // [bf: own/partner rows][df][pass]
#pragma unroll
  for (int a = 0; a < 2; ++a)
#pragma unroll
    for (int b = 0; b < 4; ++b)
#pragma unroll
      for (int p = 0; p < 3; ++p) acc[a][b][p] = (floatx4){0.f, 0.f, 0.f, 0.f};
  float bc[4] = {0.f, 0.f, 0.f, 0.f};

  for (int jj = 0; jj < JC; ++jj) {
    const int j = j0 + jj;
    // tiled-W2 (halves): this wave's d-half page = j*2+h; kg pages of 512
    const unsigned int bb0 =
        (unsigned)(j * 2 + h) * 32768u + (unsigned)(quad * 512 + l16 * 8);
    const float zv = zL[jj][w * 16 + l16];  // own build rows

#pragma unroll 2
    for (int ks = 0; ks < 16; ++ks) {
      const int par = ks & 1;
      // B frags first (latency hides under A-build + barrier)
      const unsigned int off = bb0 + (unsigned)(ks * 2048);
      half8 fh0 = *(const half8*)(W2h + off);
      half8 fh1 = *(const half8*)(W2h + off + 128);
      half8 fh2 = *(const half8*)(W2h + off + 256);
      half8 fh3 = *(const half8*)(W2h + off + 384);
      half8 fl0 = *(const half8*)(W2l + off);
      half8 fl1 = *(const half8*)(W2l + off + 128);
      half8 fl2 = *(const half8*)(W2l + off + 256);
      half8 fl3 = *(const half8*)(W2l + off + 384);

      const int ko = ks * 32 + quad * 8;
      float4 wa = *(const float4*)&w1L[jj][ko];
      float4 wc = *(const float4*)&w1L[jj][ko + 4];
      float4 ba = *(const float4*)&b1L[jj][ko];
      float4 bb = *(const float4*)&b1L[jj][ko + 4];

      // Single A-frag build: rows w*16+l16, k-octet quad
      float h0 = fmaf(zv, wa.x, ba.x), h1 = fmaf(zv, wa.y, ba.y);
      float h2 = fmaf(zv, wa.z, ba.z), h3 = fmaf(zv, wa.w, ba.w);
      float h4 = fmaf(zv, wc.x, bb.x), h5 = fmaf(zv, wc.y, bb.y);
      float h6 = fmaf(zv, wc.z, bb.z), h7 = fmaf(zv, wc.w, bb.w);
      h0 = fmaxf(h0, 0.2f * h0); h1 = fmaxf(h1, 0.2f * h1);
      h2 = fmaxf(h2, 0.2f * h2); h3 = fmaxf(h3, 0.2f * h3);
      h4 = fmaxf(h4, 0.2f * h4); h5 = fmaxf(h5, 0.2f * h5);
      h6 = fmaxf(h6, 0.2f * h6); h7 = fmaxf(h7, 0.2f * h7);
      unsigned int a0, a1, a2, a3, x0, x1, x2, x3;
      split_pair(h0, h1, a0, x0); split_pair(h2, h3, a1, x1);
      split_pair(h4, h5, a2, x2); split_pair(h6, h7, a3, x3);
      half8 fah = __builtin_bit_cast(half8, (uint4v){a0, a1, a2, a3});
      half8 fal = __builtin_bit_cast(half8, (uint4v){x0, x1, x2, x3});

      // exchange with pair partner through LDS (parity double-buffer)
      aHs[par][w][lane] = (uint4v){a0, a1, a2, a3};
      aLs[par][w][lane] = (uint4v){x0, x1, x2, x3};
      __syncthreads();
      half8 pah = __builtin_bit_cast(half8, aHs[par][pw][lane]);
      half8 pal = __builtin_bit_cast(half8, aLs[par][pw][lane]);

      // bf=0: own rows; bf=1: partner rows
      acc[0][0][0] = __builtin_amdgcn_mfma_f32_16x16x32_f16(fah, fh0, acc[0][0][0], 0, 0, 0);
      acc[0][0][1] = __builtin_amdgcn_mfma_f32_16x16x32_f16(fah, fl0, acc[0][0][1], 0, 0, 0);
      acc[0][0][2] = __builtin_amdgcn_mfma_f32_16x16x32_f16(fal, fh0, acc[0][0][2], 0, 0, 0);
      acc[0][1][0] = __builtin_amdgcn_mfma_f32_16x16x32_f16(fah, fh1, acc[0][1][0], 0, 0, 0);
      acc[0][1][1] = __builtin_amdgcn_mfma_f32_16x16x32_f16(fah, fl1, acc[0][1][1], 0, 0, 0);
      acc[0][1][2] = __builtin_amdgcn_mfma_f32_16x16x32_f16(fal, fh1, acc[0][1][2], 0, 0, 0);
      acc[0][2][0] = __builtin_amdgcn_mfma_f32_16x16x32_f16(fah, fh2, acc[0][2][0], 0, 0, 0);
      acc[0][2][1] = __builtin_amdgcn_mfma_f32_16x16x32_f16(fah, fl2, acc[0][2][1], 0, 0, 0);
      acc[0][2][2] = __builtin_amdgcn_mfma_f32_16x16x32_f16(fal, fh2, acc[0][2][2], 0, 0, 0);
      acc[0][3][0] = __builtin_amdgcn_mfma_f32_16x16x32_f16(fah, fh3, acc[0][3][0], 0, 0, 0);
      acc[0][3][1] = __builtin_amdgcn_mfma_f32_16x16x32_f16(fah, fl3, acc[0][3][1], 0, 0, 0);
      acc[0][3][2] = __builtin_amdgcn_mfma_f32_16x16x32_f16(fal, fh3, acc[0][3][2], 0, 0, 0);
      acc[1][0][0] = __builtin_amdgcn_mfma_f32_16x16x32_f16(pah, fh0, acc[1][0][0], 0, 0, 0);
      acc[1][0][1] = __builtin_amdgcn_mfma_f32_16x16x32_f16(pah, fl0, acc[1][0][1], 0, 0, 0);
      acc[1][0][2] = __builtin_amdgcn_mfma_f32_16x16x32_f16(pal, fh0, acc[1][0][2], 0, 0, 0);
      acc[1][1][0] = __builtin_amdgcn_mfma_f32_16x16x32_f16(pah, fh1, acc[1][1][0], 0, 0, 0);
      acc[1][1][1] = __builtin_amdgcn_mfma_f32_16x16x32_f16(pah, fl1, acc[1][1][1], 0, 0, 0);
      acc[1][1][2] = __builtin_amdgcn_mfma_f32_16x16x32_f16(pal, fh1, acc[1][1][2], 0, 0, 0);
      acc[1][2][0] = __builtin_amdgcn_mfma_f32_16x16x32_f16(pah, fh2, acc[1][2][0], 0, 0, 0);
      acc[1][2][1] = __builtin_amdgcn_mfma_f32_16x16x32_f16(pah, fl2, acc[1][2][1], 0, 0, 0);
      acc[1][2][2] = __builtin_amdgcn_mfma_f32_16x16x32_f16(pal, fh2, acc[1][2][2], 0, 0, 0);
      acc[1][3][0] = __builtin_amdgcn_mfma_f32_16x16x32_f16(pah, fh3, acc[1][3][0], 0, 0, 0);
      acc[1][3][1] = __builtin_amdgcn_mfma_f32_16x16x32_f16(pah, fl3, acc[1][3][1], 0, 0, 0);
      acc[1][3][2] = __builtin_amdgcn_mfma_f32_16x16x32_f16(pal, fh3, acc[1][3][2], 0, 0, 0);
    }

#pragma unroll
    for (int df = 0; df < 4; ++df) bc[df] += b2L[jj][h * 64 + df * 16 + l16];

    const int dcol = h * 64 + l16;
    float* obase = out + (size_t)j * (B_SZ * D_SZ) + dcol;
#pragma unroll
    for (int bf = 0; bf < 2; ++bf) {
      const int rb = bf ? pw : w;           // row-block of this bf
      const int brow = b0 + rb * 16 + quad * 4;
      float* orow = obase + (size_t)brow * D_SZ;
#pragma unroll
      for (int r = 0; r < 4; ++r) {
#pragma unroll
        for (int df = 0; df < 4; ++df) {
          float s = (acc[bf][df][0][r] + acc[bf][df][1][r]) +
                    (acc[bf][df][2][r] + bc[df]);
          if (jc == 0) s = tanh_fast(s);
          orow[(size_t)r * D_SZ + df * 16] = s;
        }
      }
    }
  }

  if (jc < NCH - 1) {   // chunk totals for phase-2 carries
    const int dcol = h * 64 + l16;
    float* tbase = T + (size_t)jc * (B_SZ * D_SZ) + dcol;
#pragma unroll
    for (int bf = 0; bf < 2; ++bf) {
      const int rb = bf ? pw : w;
      const int brow = b0 + rb * 16 + quad * 4;
      float* trow = tbase + (size_t)brow * D_SZ;
#pragma unroll
      for (int r = 0; r < 4; ++r) {
#pragma unroll
        for (int df = 0; df < 4; ++df) {
          trow[(size_t)r * D_SZ + df * 16] =
              (acc[bf][df][0][r] + acc[bf][df][1][r]) +
              (acc[bf][df][2][r] + bc[df]);
        }
      }
    }
  }
}

// ---- Phase 2: carry fixup + tanh for j >= JC -------------------------------
// Prefix loop fully unrolled with wave-uniform predicate (c0 uniform per
// block): all prefix loads issue in parallel instead of a serial
// runtime-bound load+add chain.
__global__ __launch_bounds__(256) void fixup_kernel(
    const float* __restrict__ T, float* __restrict__ out) {
  const int idx = blockIdx.x * 256 + threadIdx.x;
  const int d4 = idx & 31;
  const int b = (idx >> 5) & (B_SZ - 1);
  const int q = idx >> 16;                 // 0..NGRP-1 (uniform per block)
  const size_t stride = B_SZ * (D_SZ / 4);
  const size_t tix = (size_t)b * (D_SZ / 4) + d4;
  const float4* T4 = (const float4*)T;
  float4* O4 = (float4*)out;

  const int c0 = 1 + q * CPG;              // 1,4,7,10,13
  float4 carry = make_float4(0.f, 0.f, 0.f, 0.f);
#pragma unroll
  for (int c = 0; c < 1 + (NGRP - 1) * CPG; ++c) {
    if (c < c0) {                          // uniform branch, loads pipeline
      float4 tv = T4[(size_t)c * stride + tix];
      carry.x += tv.x; carry.y += tv.y; carry.z += tv.z; carry.w += tv.w;
    }
  }
#pragma unroll
  for (int cc = 0; cc < CPG; ++cc) {
    const int c = c0 + cc;
    if (cc > 0) {
      float4 tv = T4[(size_t)(c - 1) * stride + tix];
      carry.x += tv.x; carry.y += tv.y; carry.z += tv.z; carry.w += tv.w;
    }
#pragma unroll
    for (int jj = 0; jj < JC; ++jj) {
      const int j = c * JC + jj;
      const size_t oix = ((size_t)j * B_SZ + b) * (D_SZ / 4) + d4;
      float4 s = O4[oix];
      s.x = tanh_fast(s.x + carry.x);
      s.y = tanh_fast(s.y + carry.y);
      s.z = tanh_fast(s.z + carry.z);
      s.w = tanh_fast(s.w + carry.w);
      O4[oix] = s;
    }
  }
}

extern "C" void kernel_launch(void* const* d_in, const int* in_sizes, int n_in,
                              void* d_out, int out_size, void* d_ws,
                              size_t ws_size, hipStream_t stream) {
  (void)in_sizes; (void)n_in; (void)out_size; (void)ws_size;
  const float* x   = (const float*)d_in[0];
  const float* We1 = (const float*)d_in[1];
  const float* be1 = (const float*)d_in[2];
  const float* We2 = (const float*)d_in[3];
  const float* be2 = (const float*)d_in[4];
  const float* W1s = (const float*)d_in[5];
  const float* b1s = (const float*)d_in[6];
  const float* W2s = (const float*)d_in[7];
  const float* b2s = (const float*)d_in[8];
  float* out = (float*)d_out;

  // ws: z 1MB | W2h 16MB | W2l 16MB | T 15MB  -> 48 MiB
  float* zws = (float*)d_ws;
  _Float16* W2h = (_Float16*)((char*)d_ws + (1u << 20));
  _Float16* W2l = (_Float16*)((char*)d_ws + (1u << 20) + (1u << 24));
  float* T = (float*)((char*)d_ws + (1u << 20) + (2u << 24));

  prep_kernel<<<2304, 256, 0, stream>>>(W2s, W2h, W2l, x, We1, be1, We2, be2, zws);
  dec_kernel<<<512, 256, 0, stream>>>(W1s, b1s, W2h, W2l, b2s, zws, out, T);
  fixup_kernel<<<NGRP * 256, 256, 0, stream>>>(T, out);
}